// Round 2
// baseline (349.141 us; speedup 1.0000x reference)
//
#include <hip/hip_runtime.h>
#include <stdint.h>

// Two-phase tiny-LSTM (H=1, T=512, B=4096, F=25 split 12+13) + sigmoid head.
// K1 (BW-bound): stream x, compute pre-scaled gate pre-activations z' -> d_ws.
//     z'[t][b][8] fp32, pre-multiplied by -log2e (gates i,f,o) / -2log2e (g)
//     so K2's sigmoid/tanh are fma+exp2 with no extra scaling.
// K2 (latency-bound): 1 lane per (chain, lstm): serial 512-step recurrence,
//     rcp-fused gate math, 8-step register-ring prefetch of z' (L3-resident).

#define T_STEPS 512
#define F_IN    25
#define TC      32                   // timesteps per K1 tile
#define NT1     (T_STEPS / TC)       // 16 tiles
#define CH      8                    // chains per K1 block
#define TILE_F  (CH * TC * F_IN)     // 6400 floats per tile = 25 GLL dwordx4
#define LOG2E   1.44269504088896340736f
#define SC1     (-LOG2E)
#define SC2     (-2.0f * LOG2E)

typedef const __attribute__((address_space(1))) void* as1_cvp;
typedef __attribute__((address_space(3)))       void* as3_vp;

__device__ __forceinline__ void gll16(const float* gsrc, const float* ldst) {
  __builtin_amdgcn_global_load_lds((as1_cvp)(uintptr_t)gsrc,
                                   (as3_vp)(uint32_t)(uintptr_t)ldst, 16, 0, 0);
}

// ---------------- K1: gate pre-activation compute ----------------
__global__ void __launch_bounds__(256, 2)
k1_gates(const float* __restrict__ x,
         const float* __restrict__ Wih1, const float* __restrict__ b1,
         const float* __restrict__ Wih2, const float* __restrict__ b2,
         float* __restrict__ z, int B)
{
  __shared__ __align__(16) float xs[2 * TILE_F];   // 51.2 KB, double buffered

  const int tid  = threadIdx.x;
  const int wv   = tid >> 6;          // wave 0..3
  const int lane = tid & 63;
  const int b0   = blockIdx.x * CH;

  // --- per-lane GLL source descriptors (7 slots, wave w takes insts w,w+4,...) ---
  const float* gp[7];
  int ioff[7];
#pragma unroll
  for (int j = 0; j < 7; ++j) {
    const int i = wv + 4 * j;                 // GLL instruction index 0..24
    if (i < 25) {
      const int F = i * 256 + lane * 4;       // flat float idx in tile [c][TC*25]
      const int c = F / (TC * F_IN);
      const int r = F - c * (TC * F_IN);
      gp[j]   = x + (size_t)(b0 + c) * (T_STEPS * F_IN) + r;
      ioff[j] = i * 256;                      // LDS float offset of this inst
    } else { gp[j] = x; ioff[j] = -1; }
  }

  // task mapping: c = tid>>5 (8 chains), t = tid&31 (32 steps) -> 2-way banks (free)
  const int c  = tid >> 5;
  const int tl = tid & 31;

  // prologue: stage tile 0
#pragma unroll
  for (int j = 0; j < 7; ++j)
    if (ioff[j] >= 0) gll16(gp[j], xs + ioff[j]);
  __syncthreads();

  float4* __restrict__ z4 = (float4*)z;

  for (int k = 0; k < NT1; ++k) {
    // prefetch tile k+1 into the other half
    if (k + 1 < NT1) {
      const int h = (k + 1) & 1;
#pragma unroll
      for (int j = 0; j < 7; ++j)
        if (ioff[j] >= 0) gll16(gp[j] + (k + 1) * (TC * F_IN), xs + h * TILE_F + ioff[j]);
    }

    // compute from tile k
    const float* xr = xs + (k & 1) * TILE_F + c * (TC * F_IN) + tl * F_IN;
    float zz[8];
#pragma unroll
    for (int j = 0; j < 4; ++j) { zz[j] = b1[j]; zz[4 + j] = b2[j]; }
#pragma unroll
    for (int f = 0; f < 12; ++f) {
      const float xv = xr[f];
#pragma unroll
      for (int j = 0; j < 4; ++j) zz[j] = fmaf(Wih1[j * 12 + f], xv, zz[j]);
    }
#pragma unroll
    for (int f = 0; f < 13; ++f) {
      const float xv = xr[12 + f];
#pragma unroll
      for (int j = 0; j < 4; ++j) zz[4 + j] = fmaf(Wih2[j * 13 + f], xv, zz[4 + j]);
    }
    // pre-scale: i,f,o by -log2e; g by -2log2e (PyTorch gate order i,f,g,o)
    const float4 q0 = make_float4(zz[0] * SC1, zz[1] * SC1, zz[2] * SC2, zz[3] * SC1);
    const float4 q1 = make_float4(zz[4] * SC1, zz[5] * SC1, zz[6] * SC2, zz[7] * SC1);
    const size_t idx = (size_t)(k * TC + tl) * B + (b0 + c);
    z4[idx * 2]     = q0;
    z4[idx * 2 + 1] = q1;

    __syncthreads();   // tile k reads done everywhere; tile k+1 staged (BW-wait)
  }
}

// ---------------- K2: serial recurrence ----------------
__device__ __forceinline__ void lstm_step(const float4 zv,
                                          const float wi, const float wf,
                                          const float wg, const float wo,
                                          float& h, float& cc) {
  const float ei = __builtin_amdgcn_exp2f(fmaf(h, wi, zv.x));  // e^{-pi}
  const float ef = __builtin_amdgcn_exp2f(fmaf(h, wf, zv.y));  // e^{-pf}
  const float eg = __builtin_amdgcn_exp2f(fmaf(h, wg, zv.z));  // e^{-2pg}
  const float eo = __builtin_amdgcn_exp2f(fmaf(h, wo, zv.w));  // e^{-po}
  const float af  = __builtin_amdgcn_rcpf(1.0f + ef);                    // f-gate
  const float rig = __builtin_amdgcn_rcpf((1.0f + ei) * (1.0f + eg));
  const float ig  = (1.0f - eg) * rig;                                   // i*g
  cc = fmaf(af, cc, ig);
  const float ec  = __builtin_amdgcn_exp2f(cc * SC2);                    // e^{-2c}
  const float roc = __builtin_amdgcn_rcpf((1.0f + eo) * (1.0f + ec));
  h = (1.0f - ec) * roc;                                                 // o*tanh(c)
}

__global__ void __launch_bounds__(64, 1)
k2_scan(const float* __restrict__ z,
        const float* __restrict__ Whh1, const float* __restrict__ Whh2,
        const float* __restrict__ Wout, const float* __restrict__ bout,
        float* __restrict__ out, int B)
{
  const int l    = threadIdx.x;
  const int bb   = blockIdx.x * 32 + (l >> 1);   // chain
  const int lstm = l & 1;                        // 0 -> LSTM1, 1 -> LSTM2

  const float* wp = lstm ? Whh2 : Whh1;
  const float wi = SC1 * wp[0];
  const float wf = SC1 * wp[1];
  const float wg = SC2 * wp[2];
  const float wo = SC1 * wp[3];

  const float4* __restrict__ zp = (const float4*)z;
  const size_t stride = (size_t)B * 2;           // float4s per timestep
  const size_t base   = (size_t)bb * 2 + lstm;

  float4 rb[8];
#pragma unroll
  for (int j = 0; j < 8; ++j) rb[j] = zp[(size_t)j * stride + base];

  float h = 0.0f, cc = 0.0f;

  for (int t0 = 0; t0 < T_STEPS - 8; t0 += 8) {
#pragma unroll
    for (int j = 0; j < 8; ++j) {
      lstm_step(rb[j], wi, wf, wg, wo, h, cc);
      rb[j] = zp[(size_t)(t0 + j + 8) * stride + base];   // prefetch 8 ahead
    }
  }
#pragma unroll
  for (int j = 0; j < 8; ++j) lstm_step(rb[j], wi, wf, wg, wo, h, cc);

  // head: out = sigmoid(W_out . [h1,h2] + b_out)
  const float hp = __shfl_xor(h, 1);
  if (lstm == 0) {
    const float p = fmaf(Wout[0], h, fmaf(Wout[1], hp, bout[0]));
    out[bb] = __builtin_amdgcn_rcpf(1.0f + __builtin_amdgcn_exp2f(p * SC1));
  }
}

extern "C" void kernel_launch(void* const* d_in, const int* in_sizes, int n_in,
                              void* d_out, int out_size, void* d_ws, size_t ws_size,
                              hipStream_t stream) {
  const float* x    = (const float*)d_in[0];
  const float* Wih1 = (const float*)d_in[1];
  const float* Whh1 = (const float*)d_in[2];
  const float* b1   = (const float*)d_in[3];
  const float* Wih2 = (const float*)d_in[4];
  const float* Whh2 = (const float*)d_in[5];
  const float* b2   = (const float*)d_in[6];
  const float* Wout = (const float*)d_in[7];
  const float* bout = (const float*)d_in[8];
  float* out = (float*)d_out;
  float* z   = (float*)d_ws;                     // 4096*512*8 fp32 = 67 MB

  const int B = in_sizes[0] / (T_STEPS * F_IN);  // 4096

  hipLaunchKernelGGL(k1_gates, dim3(B / CH), dim3(256), 0, stream,
                     x, Wih1, b1, Wih2, b2, z, B);
  hipLaunchKernelGGL(k2_scan, dim3(B / 32), dim3(64), 0, stream,
                     z, Whh1, Whh2, Wout, bout, out, B);
}

// Round 3
// 344.633 us; speedup vs baseline: 1.0131x; 1.0131x over previous
//
#include <hip/hip_runtime.h>
#include <hip/hip_fp16.h>
#include <stdint.h>

// Two-phase tiny-LSTM (H=1, T=512, B=4096, F=25 split 12+13) + sigmoid head.
// K1 (BW-bound): stream x with direct per-thread loads (L1 coalesces), compute
//     pre-scaled gate pre-activations z' = s .* (W_ih x + b) in registers
//     (weights held in VGPRs, pre-scaled by -log2e / -2log2e), store fp16.
//     z layout: [t][b][8 halves]  (lstm1 gates i,f,g,o | lstm2 gates i,f,g,o)
// K2 (latency-bound): 1 lane per (chain,lstm); 512-step serial recurrence,
//     rcp-fused gate math (8 transcendentals/step), 8-deep register-ring
//     prefetch of z' (uint2 = 4 halves per lane per step, coalesced).

#define T_STEPS 512
#define F_IN    25
#define CH      8                    // chains per k1 block
#define LOG2E   1.44269504088896340736f
#define SC1     (-LOG2E)
#define SC2     (-2.0f * LOG2E)

// ---------------- K1: gate pre-activation compute ----------------
__global__ void __launch_bounds__(256, 2)
k1_gates(const float* __restrict__ x,
         const float* __restrict__ Wih1, const float* __restrict__ b1,
         const float* __restrict__ Wih2, const float* __restrict__ b2,
         uint4* __restrict__ z, int B)
{
  const int tid = threadIdx.x;
  const int c   = tid & 7;           // chain 0..7  (lanes 0..7 -> b0..b0+7: full-line stores)
  const int tl  = tid >> 3;          // time slot 0..31
  const int b   = blockIdx.x * CH + c;

  // ---- weights into registers, pre-scaled (i,f,o: -log2e ; g: -2log2e) ----
  float w1[48], w2[52], bb[8];
#pragma unroll
  for (int j = 0; j < 4; ++j) {
    const float s = (j == 2) ? SC2 : SC1;
#pragma unroll
    for (int f = 0; f < 12; ++f) w1[j * 12 + f] = Wih1[j * 12 + f] * s;
#pragma unroll
    for (int f = 0; f < 13; ++f) w2[j * 13 + f] = Wih2[j * 13 + f] * s;
    bb[j]     = b1[j] * s;
    bb[4 + j] = b2[j] * s;
  }

  const float* __restrict__ xrow = x + (size_t)b * (T_STEPS * F_IN);

  for (int k = 0; k < T_STEPS / 32; ++k) {     // 16 iterations
    const int t = k * 32 + tl;
    const float* __restrict__ xr = xrow + t * F_IN;

    float xv[25];
#pragma unroll
    for (int f = 0; f < 25; ++f) xv[f] = xr[f];

    float zz[8];
#pragma unroll
    for (int j = 0; j < 8; ++j) zz[j] = bb[j];
#pragma unroll
    for (int f = 0; f < 12; ++f) {
#pragma unroll
      for (int j = 0; j < 4; ++j) zz[j] = fmaf(w1[j * 12 + f], xv[f], zz[j]);
    }
#pragma unroll
    for (int f = 0; f < 13; ++f) {
#pragma unroll
      for (int j = 0; j < 4; ++j) zz[4 + j] = fmaf(w2[j * 13 + f], xv[12 + f], zz[4 + j]);
    }

    const __half2 p0 = __floats2half2_rn(zz[0], zz[1]);
    const __half2 p1 = __floats2half2_rn(zz[2], zz[3]);
    const __half2 p2 = __floats2half2_rn(zz[4], zz[5]);
    const __half2 p3 = __floats2half2_rn(zz[6], zz[7]);
    uint4 q;
    q.x = *(const unsigned int*)&p0;
    q.y = *(const unsigned int*)&p1;
    q.z = *(const unsigned int*)&p2;
    q.w = *(const unsigned int*)&p3;
    z[(size_t)t * B + b] = q;                  // lanes 0..7 -> one full 128B line
  }
}

// ---------------- K2: serial recurrence ----------------
__device__ __forceinline__ void lstm_step(const uint2 v,
                                          const float wi, const float wf,
                                          const float wg, const float wo,
                                          float& h, float& cc) {
  const __half2 h01 = *(const __half2*)&v.x;
  const __half2 h23 = *(const __half2*)&v.y;
  const float2 f01 = __half22float2(h01);      // z'_i, z'_f
  const float2 f23 = __half22float2(h23);      // z'_g, z'_o
  const float ei = __builtin_amdgcn_exp2f(fmaf(h, wi, f01.x));  // e^{-pi}
  const float ef = __builtin_amdgcn_exp2f(fmaf(h, wf, f01.y));  // e^{-pf}
  const float eg = __builtin_amdgcn_exp2f(fmaf(h, wg, f23.x));  // e^{-2pg}
  const float eo = __builtin_amdgcn_exp2f(fmaf(h, wo, f23.y));  // e^{-po}
  const float af  = __builtin_amdgcn_rcpf(1.0f + ef);                 // f-gate
  const float rig = __builtin_amdgcn_rcpf((1.0f + ei) * (1.0f + eg));
  const float ig  = (1.0f - eg) * rig;                                // i*tanh(g)
  cc = fmaf(af, cc, ig);
  const float ec  = __builtin_amdgcn_exp2f(cc * SC2);                 // e^{-2c}
  const float roc = __builtin_amdgcn_rcpf((1.0f + eo) * (1.0f + ec));
  h = (1.0f - ec) * roc;                                              // o*tanh(c)
}

__global__ void __launch_bounds__(64, 1)
k2_scan(const uint2* __restrict__ z,
        const float* __restrict__ Whh1, const float* __restrict__ Whh2,
        const float* __restrict__ Wout, const float* __restrict__ bout,
        float* __restrict__ out, int B)
{
  const int l    = threadIdx.x;
  const int bb   = blockIdx.x * 32 + (l >> 1);   // chain
  const int lstm = l & 1;                        // 0 -> LSTM1, 1 -> LSTM2

  const float* wp = lstm ? Whh2 : Whh1;
  const float wi = SC1 * wp[0];
  const float wf = SC1 * wp[1];
  const float wg = SC2 * wp[2];
  const float wo = SC1 * wp[3];

  const uint2* __restrict__ zp = z + (size_t)bb * 2 + lstm;
  const size_t stride = (size_t)B * 2;           // uint2 per timestep

  uint2 rb[8];
#pragma unroll
  for (int j = 0; j < 8; ++j) rb[j] = zp[(size_t)j * stride];

  float h = 0.0f, cc = 0.0f;

  for (int t0 = 0; t0 < T_STEPS - 8; t0 += 8) {
#pragma unroll
    for (int j = 0; j < 8; ++j) {
      const uint2 v = rb[j];
      rb[j] = zp[(size_t)(t0 + j + 8) * stride];   // prefetch 8 ahead
      lstm_step(v, wi, wf, wg, wo, h, cc);
    }
  }
#pragma unroll
  for (int j = 0; j < 8; ++j) lstm_step(rb[j], wi, wf, wg, wo, h, cc);

  // head: out = sigmoid(W_out . [h1,h2] + b_out)
  const float hp = __shfl_xor(h, 1);
  if (lstm == 0) {
    const float p = fmaf(Wout[0], h, fmaf(Wout[1], hp, bout[0]));
    out[bb] = __builtin_amdgcn_rcpf(1.0f + __builtin_amdgcn_exp2f(p * SC1));
  }
}

extern "C" void kernel_launch(void* const* d_in, const int* in_sizes, int n_in,
                              void* d_out, int out_size, void* d_ws, size_t ws_size,
                              hipStream_t stream) {
  const float* x    = (const float*)d_in[0];
  const float* Wih1 = (const float*)d_in[1];
  const float* Whh1 = (const float*)d_in[2];
  const float* b1   = (const float*)d_in[3];
  const float* Wih2 = (const float*)d_in[4];
  const float* Whh2 = (const float*)d_in[5];
  const float* b2   = (const float*)d_in[6];
  const float* Wout = (const float*)d_in[7];
  const float* bout = (const float*)d_in[8];
  float* out = (float*)d_out;

  const int B = in_sizes[0] / (T_STEPS * F_IN);  // 4096

  hipLaunchKernelGGL(k1_gates, dim3(B / CH), dim3(256), 0, stream,
                     x, Wih1, b1, Wih2, b2, (uint4*)d_ws, B);
  hipLaunchKernelGGL(k2_scan, dim3(B / 32), dim3(64), 0, stream,
                     (const uint2*)d_ws, Whh1, Whh2, Wout, bout, out, B);
}